// Round 10
// baseline (23.607 us; speedup 1.0000x reference)
//
#include <hip/hip_runtime.h>

// Problem constants: V=50000, F=100000, H=W=256, K=1, B=4, J=256
#define NPIX  65536
#define BB    4
#define JJ    256

// Output layout (concatenated flat, fp32):
//   colors  : (B,H,W,3)  base 0
//   diffuse : (B,H,W,3)  base 786432
//   texels  : (1,H,W,3)  base 1572864
//   normals : (B,H,W,3)  base 1769472

struct F3 { float x, y, z; };
struct I3 { int x, y, z; };

// Grid: 1024 blocks x 256 threads. 1 pixel per thread, all 256 lights.
// No LDS, no barriers — waves fully independent (no convoy points).
// Lights are read as per-lane float4 loads of wave-uniform addresses
// (hardware broadcast, L1-resident after first pass). The J-loop is
// software-pipelined at source level with TWO NAMED register buffers
// (A/B, 6 float4 each = 4 lights) so the compiler issues group g+1's
// loads before computing group g -> partial vmcnt waits, no full drain.
__global__ __launch_bounds__(256, 4) void shade_kernel(
    const int*   __restrict__ p2f,    // (1,H,W,1) int32
    const float* __restrict__ bary,   // (1,H,W,1,3)
    const int*   __restrict__ faces,  // (F,3)
    const float* __restrict__ vnorm,  // (V,3)
    const float* __restrict__ dirs,   // (B,J,3)
    const float* __restrict__ env,    // (B,J,3)
    const float* __restrict__ tex,    // (1,H,W,3)
    float*       __restrict__ out)
{
    const int b = blockIdx.x >> 8;                         // batch (block-uniform)
    const int p = ((blockIdx.x & 255) << 8) | threadIdx.x; // pixel 0..65535

    // ---- gather + normalize (own pixel) ----
    const int f  = p2f[p];
    const I3 vv = ((const I3*)faces)[f];
    const F3 bc = ((const F3*)bary)[p];
    const F3 a0 = ((const F3*)vnorm)[vv.x];
    const F3 a1 = ((const F3*)vnorm)[vv.y];
    const F3 a2 = ((const F3*)vnorm)[vv.z];
    float nx = bc.x*a0.x + bc.y*a1.x + bc.z*a2.x;
    float ny = bc.x*a0.y + bc.y*a1.y + bc.z*a2.y;
    float nz = bc.x*a0.z + bc.y*a1.z + bc.z*a2.z;
    const float inv = 1.0f / fmaxf(sqrtf(nx*nx + ny*ny + nz*nz), 1e-6f);
    nx *= inv; ny *= inv; nz *= inv;

    // ---- J-loop: 64 groups of 4 lights, register double-buffered ----
    const float4* __restrict__ d4 = (const float4*)(dirs + b * (JJ*3)); // 16B-aligned (3072B/batch)
    const float4* __restrict__ e4 = (const float4*)(env  + b * (JJ*3));

    float ar = 0.f, ag = 0.f, ab = 0.f;
    float4 DA0, DA1, DA2, EA0, EA1, EA2;   // buffer A: 4 lights
    float4 DB0, DB1, DB2, EB0, EB1, EB2;   // buffer B

#define LOADG(P0, P1, P2, Q0, Q1, Q2, gi)                                \
    P0 = d4[(gi)*3 + 0]; P1 = d4[(gi)*3 + 1]; P2 = d4[(gi)*3 + 2];       \
    Q0 = e4[(gi)*3 + 0]; Q1 = e4[(gi)*3 + 1]; Q2 = e4[(gi)*3 + 2];

#define LIGHT(dx, dy, dz, er, eg, eb) {                                  \
    float w = fmaf(nz, (dz), fmaf(ny, (dy), nx * (dx)));                 \
    w = fminf(fmaxf(w, 0.f), 1.f);  /* v_med3_f32 */                     \
    ar = fmaf((er), w, ar); ag = fmaf((eg), w, ag); ab = fmaf((eb), w, ab); }

#define COMPUTEG(P0, P1, P2, Q0, Q1, Q2)                                 \
    LIGHT(P0.x, P0.y, P0.z, Q0.x, Q0.y, Q0.z)                            \
    LIGHT(P0.w, P1.x, P1.y, Q0.w, Q1.x, Q1.y)                            \
    LIGHT(P1.z, P1.w, P2.x, Q1.z, Q1.w, Q2.x)                            \
    LIGHT(P2.y, P2.z, P2.w, Q2.y, Q2.z, Q2.w)

    LOADG(DA0, DA1, DA2, EA0, EA1, EA2, 0);
    for (int g = 0; g < 31; ++g) {       // each iteration: groups 2g and 2g+1
        LOADG(DB0, DB1, DB2, EB0, EB1, EB2, 2*g + 1);
        COMPUTEG(DA0, DA1, DA2, EA0, EA1, EA2);
        LOADG(DA0, DA1, DA2, EA0, EA1, EA2, 2*g + 2);
        COMPUTEG(DB0, DB1, DB2, EB0, EB1, EB2);
    }
    LOADG(DB0, DB1, DB2, EB0, EB1, EB2, 63);   // A holds group 62
    COMPUTEG(DA0, DA1, DA2, EA0, EA1, EA2);
    COMPUTEG(DB0, DB1, DB2, EB0, EB1, EB2);

#undef LOADG
#undef LIGHT
#undef COMPUTEG

    // ---- outputs ----
    const F3 tv = ((const F3*)tex)[p];
    const int o = 3 * (b * NPIX + p);

    out[o + 0] = ar * tv.x;              // colors = diffuse * texels
    out[o + 1] = ag * tv.y;
    out[o + 2] = ab * tv.z;

    float* __restrict__ dif = out + 3 * BB * NPIX;
    dif[o + 0] = ar;
    dif[o + 1] = ag;
    dif[o + 2] = ab;

    float* __restrict__ nor = out + 3 * BB * NPIX * 2 + 3 * NPIX;
    nor[o + 0] = nx;
    nor[o + 1] = ny;
    nor[o + 2] = nz;

    if (b == 0) {                        // texels passthrough
        float* __restrict__ tx = out + 3 * BB * NPIX * 2;
        tx[3*p + 0] = tv.x;
        tx[3*p + 1] = tv.y;
        tx[3*p + 2] = tv.z;
    }
}

extern "C" void kernel_launch(void* const* d_in, const int* in_sizes, int n_in,
                              void* d_out, int out_size, void* d_ws, size_t ws_size,
                              hipStream_t stream) {
    const int*   p2f   = (const int*)  d_in[0];
    const float* bary  = (const float*)d_in[1];
    const int*   faces = (const int*)  d_in[2];
    // d_in[3] = verts (unused)
    const float* vnorm = (const float*)d_in[4];
    const float* dirs  = (const float*)d_in[5];
    const float* env   = (const float*)d_in[6];
    const float* tex   = (const float*)d_in[7];
    float* out = (float*)d_out;

    const int grid = BB * (NPIX / 256);   // 4 * 256 = 1024 blocks
    shade_kernel<<<grid, 256, 0, stream>>>(
        p2f, bary, faces, vnorm, dirs, env, tex, out);
}

// Round 11
// 21.516 us; speedup vs baseline: 1.0972x; 1.0972x over previous
//
#include <hip/hip_runtime.h>

// Problem constants: V=50000, F=100000, H=W=256, K=1, B=4, J=256
#define NPIX  65536
#define BB    4
#define JJ    256

// Output layout (concatenated flat, fp32):
//   colors  : (B,H,W,3)  base 0
//   diffuse : (B,H,W,3)  base 786432
//   texels  : (1,H,W,3)  base 1572864
//   normals : (B,H,W,3)  base 1769472

struct F3 { float x, y, z; };
struct I3 { int x, y, z; };

// Grid: 2048 blocks x 256 threads (8 blocks/CU = 32 waves/CU, 100% occupancy).
//   b     = blockIdx.x >> 9      (batch, block-uniform)
//   pbase = (blockIdx.x & 511)*128
// Waves 0,1 -> light half 0; waves 2,3 -> light half 1 (jh via readfirstlane
// -> provably SGPR -> s_load for lights; round-4 lesson). Each thread: one
// pixel slot q (0..127), 128 lights. Gather deduped: jh==0 threads gather
// once per pixel into LDS. Single 2-way merge (vs R6's 4-way).
__global__ __launch_bounds__(256, 8) void shade_kernel(
    const int*   __restrict__ p2f,    // (1,H,W,1) int32
    const float* __restrict__ bary,   // (1,H,W,1,3)
    const int*   __restrict__ faces,  // (F,3)
    const float* __restrict__ vnorm,  // (V,3)
    const float* __restrict__ dirs,   // (B,J,3)
    const float* __restrict__ env,    // (B,J,3)
    const float* __restrict__ tex,    // (1,H,W,3)
    float*       __restrict__ out)
{
    const int b     = blockIdx.x >> 9;                     // batch (block-uniform)
    const int pbase = (blockIdx.x & 511) << 7;             // first pixel of block
    const int t     = threadIdx.x;
    const int i     = t & 63;
    const int w     = t >> 6;                              // wave 0..3
    const int jh    = __builtin_amdgcn_readfirstlane(w >> 1); // light half (SGPR)
    const int q     = ((w & 1) << 6) | i;                  // pixel slot 0..127

    __shared__ float4 nlds[128];                           // 2 KB normals
    __shared__ float  part[128][3];                        // 1.5 KB partials

    const F3* __restrict__ bary3  = (const F3*)bary;
    const I3* __restrict__ faces3 = (const I3*)faces;
    const F3* __restrict__ vn3    = (const F3*)vnorm;
    const F3* __restrict__ tex3   = (const F3*)tex;

    // ---- Phase 1: jh==0 threads gather + normalize (once per pixel) ----
    if (jh == 0) {
        const int p = pbase + q;
        const int f = p2f[p];
        const I3 vv = faces3[f];
        const F3 bc = bary3[p];
        const F3 a0 = vn3[vv.x];
        const F3 a1 = vn3[vv.y];
        const F3 a2 = vn3[vv.z];
        float nx = bc.x*a0.x + bc.y*a1.x + bc.z*a2.x;
        float ny = bc.x*a0.y + bc.y*a1.y + bc.z*a2.y;
        float nz = bc.x*a0.z + bc.y*a1.z + bc.z*a2.z;
        const float inv = 1.0f / fmaxf(sqrtf(nx*nx + ny*ny + nz*nz), 1e-6f);
        nx *= inv; ny *= inv; nz *= inv;
        nlds[q] = make_float4(nx, ny, nz, 0.f);

        // normals output (this block's batch copy)
        float* __restrict__ nor = out + (3*BB*NPIX*2 + 3*NPIX);
        const int o = 3*(b*NPIX + p);
        nor[o+0] = nx; nor[o+1] = ny; nor[o+2] = nz;

        // texels passthrough (batch-0 blocks cover all pixels)
        if (b == 0) {
            const F3 tv = tex3[p];
            float* __restrict__ tx = out + 3*BB*NPIX*2;
            tx[3*p+0] = tv.x; tx[3*p+1] = tv.y; tx[3*p+2] = tv.z;
        }
    }
    __syncthreads();

    // ---- Phase 2: 128 lights (wave-uniform scalar loads), 7 VALU/pair ----
    const float4 n = nlds[q];
    float ar = 0.f, ag = 0.f, ab = 0.f;
    const float* __restrict__ dp = dirs + b*(JJ*3) + jh*(128*3);
    const float* __restrict__ ep = env  + b*(JJ*3) + jh*(128*3);

    #pragma unroll 8
    for (int j = 0; j < 128; ++j) {
        const float dx = dp[3*j+0], dy = dp[3*j+1], dz = dp[3*j+2];
        const float er = ep[3*j+0], eg = ep[3*j+1], eb = ep[3*j+2];
        float wgt = fmaf(n.z, dz, fmaf(n.y, dy, n.x*dx));
        // |n|<=1, |d|=1 -> dot<=1 always; only the lower clip can bind
        wgt = fmaxf(wgt, 0.f);
        ar = fmaf(er, wgt, ar); ag = fmaf(eg, wgt, ag); ab = fmaf(eb, wgt, ab);
    }

    // ---- Phase 3: 2-way merge via LDS, jh==0 threads store ----
    if (jh == 1) {
        part[q][0] = ar; part[q][1] = ag; part[q][2] = ab;
    }
    __syncthreads();

    if (jh == 0) {
        const float sr = ar + part[q][0];
        const float sg = ag + part[q][1];
        const float sb = ab + part[q][2];

        const int p = pbase + q;
        const F3 tv = tex3[p];
        const int o = 3*(b*NPIX + p);
        out[o+0] = sr*tv.x; out[o+1] = sg*tv.y; out[o+2] = sb*tv.z;

        float* __restrict__ dif = out + 3*BB*NPIX;
        dif[o+0] = sr; dif[o+1] = sg; dif[o+2] = sb;
    }
}

extern "C" void kernel_launch(void* const* d_in, const int* in_sizes, int n_in,
                              void* d_out, int out_size, void* d_ws, size_t ws_size,
                              hipStream_t stream) {
    const int*   p2f   = (const int*)  d_in[0];
    const float* bary  = (const float*)d_in[1];
    const int*   faces = (const int*)  d_in[2];
    // d_in[3] = verts (unused)
    const float* vnorm = (const float*)d_in[4];
    const float* dirs  = (const float*)d_in[5];
    const float* env   = (const float*)d_in[6];
    const float* tex   = (const float*)d_in[7];
    float* out = (float*)d_out;

    const int grid = BB * (NPIX / 128);   // 4 * 512 = 2048 blocks
    shade_kernel<<<grid, 256, 0, stream>>>(
        p2f, bary, faces, vnorm, dirs, env, tex, out);
}

// Round 12
// 19.957 us; speedup vs baseline: 1.1829x; 1.0781x over previous
//
#include <hip/hip_runtime.h>

// Problem constants: V=50000, F=100000, H=W=256, K=1, B=4, J=256
#define NPIX  65536
#define BB    4
#define JJ    256

// Output layout (concatenated flat, fp32):
//   colors  : (B,H,W,3)  base 0
//   diffuse : (B,H,W,3)  base 786432
//   texels  : (1,H,W,3)  base 1572864
//   normals : (B,H,W,3)  base 1769472

struct F3 { float x, y, z; };
struct I3 { int x, y, z; };

// Grid: 1024 blocks x 512 threads (8 waves/block; 8192 waves = 8/SIMD).
// Block = 64 pixels x ALL 4 batches. Wave w handles (b = w>>1, jh = w&1):
// both readfirstlane-pinned -> light addrs wave-uniform -> s_load path.
// Gather (p2f->faces->vnorm chain) runs ONCE per pixel (wave 0), not once
// per (pixel,batch): 4x less scattered-load work than R6.
// Each lane: 1 pixel, 128 lights. jh pairs merge via LDS.
__global__ __launch_bounds__(512, 8) void shade_kernel(
    const int*   __restrict__ p2f,    // (1,H,W,1) int32
    const float* __restrict__ bary,   // (1,H,W,1,3)
    const int*   __restrict__ faces,  // (F,3)
    const float* __restrict__ vnorm,  // (V,3)
    const float* __restrict__ dirs,   // (B,J,3)
    const float* __restrict__ env,    // (B,J,3)
    const float* __restrict__ tex,    // (1,H,W,3)
    float*       __restrict__ out)
{
    const int pbase = blockIdx.x << 6;                 // 64 pixels per block
    const int t     = threadIdx.x;
    const int L     = t & 63;                          // lane = local pixel
    const int b     = __builtin_amdgcn_readfirstlane(t >> 7);        // batch 0..3
    const int jh    = __builtin_amdgcn_readfirstlane((t >> 6) & 1);  // light half

    __shared__ float4 nlds[64];                        // 1 KB normals
    __shared__ float4 part[4][64];                     // 4 KB partials

    const F3* __restrict__ bary3  = (const F3*)bary;
    const I3* __restrict__ faces3 = (const I3*)faces;
    const F3* __restrict__ vn3    = (const F3*)vnorm;
    const F3* __restrict__ tex3   = (const F3*)tex;

    // ---- Phase 1: wave 0 gathers + normalizes 64 normals (once per pixel) ----
    if (t < 64) {
        const int p = pbase + t;
        const int f = p2f[p];
        const I3 vv = faces3[f];
        const F3 bc = bary3[p];
        const F3 a0 = vn3[vv.x];
        const F3 a1 = vn3[vv.y];
        const F3 a2 = vn3[vv.z];
        float nx = bc.x*a0.x + bc.y*a1.x + bc.z*a2.x;
        float ny = bc.x*a0.y + bc.y*a1.y + bc.z*a2.y;
        float nz = bc.x*a0.z + bc.y*a1.z + bc.z*a2.z;
        const float inv = 1.0f / fmaxf(sqrtf(nx*nx + ny*ny + nz*nz), 1e-6f);
        nx *= inv; ny *= inv; nz *= inv;
        nlds[t] = make_float4(nx, ny, nz, 0.f);
    }
    __syncthreads();

    // ---- Phase 2: 128 lights for (b, jh); wave-uniform scalar loads ----
    const float4 n = nlds[L];
    float ar = 0.f, ag = 0.f, ab = 0.f;
    const float* __restrict__ dp = dirs + b*(JJ*3) + jh*(128*3);
    const float* __restrict__ ep = env  + b*(JJ*3) + jh*(128*3);

    #pragma unroll 16
    for (int j = 0; j < 128; ++j) {
        const float dx = dp[3*j+0], dy = dp[3*j+1], dz = dp[3*j+2];
        const float er = ep[3*j+0], eg = ep[3*j+1], eb = ep[3*j+2];
        float wgt = fmaf(n.z, dz, fmaf(n.y, dy, n.x*dx));
        // |n|<=1, |d|=1 -> dot<=1; only the lower clip can bind
        wgt = fmaxf(wgt, 0.f);
        ar = fmaf(er, wgt, ar); ag = fmaf(eg, wgt, ag); ab = fmaf(eb, wgt, ab);
    }

    // ---- Phase 3: jh==1 waves publish partials + write normals/texels ----
    if (jh == 1) {
        part[b][L] = make_float4(ar, ag, ab, 0.f);

        const int p = pbase + L;
        float* __restrict__ nor = out + (3*BB*NPIX*2 + 3*NPIX);
        const int o = 3*(b*NPIX + p);
        nor[o+0] = n.x; nor[o+1] = n.y; nor[o+2] = n.z;   // batch-b copy

        if (b == 0) {                                     // texels passthrough
            const F3 tv = tex3[p];
            float* __restrict__ tx = out + 3*BB*NPIX*2;
            tx[3*p+0] = tv.x; tx[3*p+1] = tv.y; tx[3*p+2] = tv.z;
        }
    }
    __syncthreads();

    // ---- Phase 4: jh==0 waves reduce + write colors/diffuse (coalesced) ----
    if (jh == 0) {
        const float4 q = part[b][L];
        const float sr = ar + q.x;
        const float sg = ag + q.y;
        const float sb = ab + q.z;

        const int p = pbase + L;
        const F3 tv = tex3[p];
        const int o = 3*(b*NPIX + p);
        out[o+0] = sr*tv.x; out[o+1] = sg*tv.y; out[o+2] = sb*tv.z;

        float* __restrict__ dif = out + 3*BB*NPIX;
        dif[o+0] = sr; dif[o+1] = sg; dif[o+2] = sb;
    }
}

extern "C" void kernel_launch(void* const* d_in, const int* in_sizes, int n_in,
                              void* d_out, int out_size, void* d_ws, size_t ws_size,
                              hipStream_t stream) {
    const int*   p2f   = (const int*)  d_in[0];
    const float* bary  = (const float*)d_in[1];
    const int*   faces = (const int*)  d_in[2];
    // d_in[3] = verts (unused)
    const float* vnorm = (const float*)d_in[4];
    const float* dirs  = (const float*)d_in[5];
    const float* env   = (const float*)d_in[6];
    const float* tex   = (const float*)d_in[7];
    float* out = (float*)d_out;

    const int grid = NPIX / 64;            // 1024 blocks
    shade_kernel<<<grid, 512, 0, stream>>>(
        p2f, bary, faces, vnorm, dirs, env, tex, out);
}

// Round 13
// 17.539 us; speedup vs baseline: 1.3459x; 1.1379x over previous
//
#include <hip/hip_runtime.h>

// Problem constants: V=50000, F=100000, H=W=256, K=1, B=4, J=256
#define NPIX  65536
#define BB    4
#define JJ    256

// Output layout (concatenated flat, fp32):
//   colors  : (B,H,W,3)  base 0
//   diffuse : (B,H,W,3)  base 786432
//   texels  : (1,H,W,3)  base 1572864
//   normals : (B,H,W,3)  base 1769472

struct F3 { float x, y, z; };
struct I3 { int x, y, z; };

typedef float f2 __attribute__((ext_vector_type(2)));

// Grid: 512 blocks x 1024 threads (16 waves/block; 8192 waves = 8/SIMD).
// Block = 128 pixels x 4 batches x 4 light-quarters.
// Wave w: b = w>>2, jq = w&3 (readfirstlane-pinned -> s_load lights).
// Lane L packs pixels (pbase+L, pbase+64+L) as <2 x float> halves:
// per light, 7 v_pk_* instructions shade 2 pixels (half the wave-instr
// count of the scalar kernels R3..R12 — testing the instruction-count wall).
__global__ __launch_bounds__(1024, 8) void shade_kernel(
    const int*   __restrict__ p2f,    // (1,H,W,1) int32
    const float* __restrict__ bary,   // (1,H,W,1,3)
    const int*   __restrict__ faces,  // (F,3)
    const float* __restrict__ vnorm,  // (V,3)
    const float* __restrict__ dirs,   // (B,J,3)
    const float* __restrict__ env,    // (B,J,3)
    const float* __restrict__ tex,    // (1,H,W,3)
    float*       __restrict__ out)
{
    const int t     = threadIdx.x;
    const int L     = t & 63;                                   // lane
    const int jq    = __builtin_amdgcn_readfirstlane((t >> 6) & 3);  // light quarter
    const int b     = __builtin_amdgcn_readfirstlane(t >> 8);        // batch
    const int pbase = blockIdx.x << 7;                          // 128 px/block

    __shared__ float4 nlds[128];                                // 2 KB normals
    __shared__ f2     part[4][4][64][3];                        // 24 KB partials

    const F3* __restrict__ bary3  = (const F3*)bary;
    const I3* __restrict__ faces3 = (const I3*)faces;
    const F3* __restrict__ vn3    = (const F3*)vnorm;
    const F3* __restrict__ tex3   = (const F3*)tex;

    // ---- Phase 1: threads 0..127 gather + normalize (once per pixel) ----
    if (t < 128) {
        const int p = pbase + t;
        const int f = p2f[p];
        const I3 vv = faces3[f];
        const F3 bc = bary3[p];
        const F3 a0 = vn3[vv.x];
        const F3 a1 = vn3[vv.y];
        const F3 a2 = vn3[vv.z];
        float nx = bc.x*a0.x + bc.y*a1.x + bc.z*a2.x;
        float ny = bc.x*a0.y + bc.y*a1.y + bc.z*a2.y;
        float nz = bc.x*a0.z + bc.y*a1.z + bc.z*a2.z;
        const float inv = 1.0f / fmaxf(sqrtf(nx*nx + ny*ny + nz*nz), 1e-6f);
        nx *= inv; ny *= inv; nz *= inv;
        nlds[t] = make_float4(nx, ny, nz, 0.f);
    }
    __syncthreads();

    // ---- Phase 2: 64 lights for (b,jq); 2 pixels/lane, packed f32 ----
    const float4 nA = nlds[L];                                  // pixel pbase+L
    const float4 nB = nlds[64 + L];                             // pixel pbase+64+L
    const f2 nx = {nA.x, nB.x};
    const f2 ny = {nA.y, nB.y};
    const f2 nz = {nA.z, nB.z};
    f2 ar = {0.f, 0.f}, ag = {0.f, 0.f}, ab = {0.f, 0.f};

    const float* __restrict__ dp = dirs + b*(JJ*3) + jq*(64*3);
    const float* __restrict__ ep = env  + b*(JJ*3) + jq*(64*3);

    #pragma unroll 8
    for (int j = 0; j < 64; ++j) {
        const float dx = dp[3*j+0], dy = dp[3*j+1], dz = dp[3*j+2];
        const float er = ep[3*j+0], eg = ep[3*j+1], eb = ep[3*j+2];
        f2 w = __builtin_elementwise_fma(nz, (f2){dz, dz},
               __builtin_elementwise_fma(ny, (f2){dy, dy}, nx * (f2){dx, dx}));
        w = __builtin_elementwise_max(w, (f2){0.f, 0.f});       // v_pk_max_f32
        ar = __builtin_elementwise_fma((f2){er, er}, w, ar);
        ag = __builtin_elementwise_fma((f2){eg, eg}, w, ag);
        ab = __builtin_elementwise_fma((f2){eb, eb}, w, ab);
    }

    // ---- Phase 3: jq!=0 publish partials; jq==1 writes normals, (2,b0) texels ----
    if (jq != 0) {
        part[jq][b][L][0] = ar;
        part[jq][b][L][1] = ag;
        part[jq][b][L][2] = ab;
    }
    if (jq == 1) {                                              // normals, batch b
        float* __restrict__ nor = out + (3*BB*NPIX*2 + 3*NPIX);
        const int pA = pbase + L, pB = pbase + 64 + L;
        const int oA = 3*(b*NPIX + pA), oB = 3*(b*NPIX + pB);
        nor[oA+0] = nA.x; nor[oA+1] = nA.y; nor[oA+2] = nA.z;
        nor[oB+0] = nB.x; nor[oB+1] = nB.y; nor[oB+2] = nB.z;
    }
    if (jq == 2 && b == 0) {                                    // texels passthrough
        float* __restrict__ tx = out + 3*BB*NPIX*2;
        const int pA = pbase + L, pB = pbase + 64 + L;
        const F3 tA = tex3[pA], tB = tex3[pB];
        tx[3*pA+0] = tA.x; tx[3*pA+1] = tA.y; tx[3*pA+2] = tA.z;
        tx[3*pB+0] = tB.x; tx[3*pB+1] = tB.y; tx[3*pB+2] = tB.z;
    }
    __syncthreads();

    // ---- Phase 4: jq==0 waves reduce quarters + store colors/diffuse ----
    if (jq == 0) {
        f2 sr = ar, sg = ag, sb = ab;
        #pragma unroll
        for (int q = 1; q < 4; ++q) {
            sr += part[q][b][L][0];
            sg += part[q][b][L][1];
            sb += part[q][b][L][2];
        }
        const int pA = pbase + L, pB = pbase + 64 + L;
        const F3 tA = tex3[pA], tB = tex3[pB];
        const int oA = 3*(b*NPIX + pA), oB = 3*(b*NPIX + pB);

        out[oA+0] = sr.x*tA.x; out[oA+1] = sg.x*tA.y; out[oA+2] = sb.x*tA.z;
        out[oB+0] = sr.y*tB.x; out[oB+1] = sg.y*tB.y; out[oB+2] = sb.y*tB.z;

        float* __restrict__ dif = out + 3*BB*NPIX;
        dif[oA+0] = sr.x; dif[oA+1] = sg.x; dif[oA+2] = sb.x;
        dif[oB+0] = sr.y; dif[oB+1] = sg.y; dif[oB+2] = sb.y;
    }
}

extern "C" void kernel_launch(void* const* d_in, const int* in_sizes, int n_in,
                              void* d_out, int out_size, void* d_ws, size_t ws_size,
                              hipStream_t stream) {
    const int*   p2f   = (const int*)  d_in[0];
    const float* bary  = (const float*)d_in[1];
    const int*   faces = (const int*)  d_in[2];
    // d_in[3] = verts (unused)
    const float* vnorm = (const float*)d_in[4];
    const float* dirs  = (const float*)d_in[5];
    const float* env   = (const float*)d_in[6];
    const float* tex   = (const float*)d_in[7];
    float* out = (float*)d_out;

    const int grid = NPIX / 128;            // 512 blocks
    shade_kernel<<<grid, 1024, 0, stream>>>(
        p2f, bary, faces, vnorm, dirs, env, tex, out);
}